// Round 9
// baseline (601.675 us; speedup 1.0000x reference)
//
#include <hip/hip_runtime.h>

constexpr int B_  = 4;
constexpr int T_  = 4096;
constexpr int C_  = 1024;
constexpr int H_  = 64;
constexpr int BT_ = B_ * T_;
constexpr int NUNIT_ = 1152;   // 512-key work units per batch: sum_qt (qt/32+1)

typedef __attribute__((ext_vector_type(4))) float f32x4;
typedef __attribute__((ext_vector_type(8))) short bf16x8;
typedef __attribute__((ext_vector_type(8))) unsigned short u16x8;
typedef __attribute__((ext_vector_type(4))) unsigned short u16x4;
typedef __attribute__((ext_vector_type(2))) unsigned int u32x2;

__device__ __forceinline__ unsigned short f32_to_bf16(float f) {
    union { float f; unsigned int u; } v;
    v.f = f;
    unsigned int r = v.u + 0x7FFFu + ((v.u >> 16) & 1u);  // RNE
    return (unsigned short)(r >> 16);
}
__device__ __forceinline__ float bf16_to_f32(unsigned short us) {
    union { unsigned int u; float f; } v;
    v.u = (unsigned int)us << 16;
    return v.f;
}
__device__ __forceinline__ float exp2_hw(float x) {
    return __builtin_amdgcn_exp2f(x);
}
// HW packed f32->bf16 (RNE, same rounding as f32_to_bf16): 1 instr for 2 vals.
__device__ __forceinline__ unsigned int cvt_pk_bf16(float lo, float hi) {
    unsigned int r;
    asm("v_cvt_pk_bf16_f32 %0, %1, %2" : "=v"(r) : "v"(lo), "v"(hi));
    return r;
}

// ---- Kernel 0: W -> fragment-order Wt; also zero the 32 progress flags -----
__global__ __launch_bounds__(256) void wconv_kernel(
    const float* __restrict__ Wq, const float* __restrict__ Wk,
    const float* __restrict__ Wv, unsigned short* __restrict__ Wt,
    unsigned int* __restrict__ segcnt)
{
    const int tid  = threadIdx.x;
    if (blockIdx.x == 0 && tid < 32) segcnt[tid] = 0;   // poisoned each iter
    const int wid  = blockIdx.x * 4 + (tid >> 6);   // 0..383 = 12 ntiles x 32 ksteps
    const int lane = tid & 63;
    const int q    = lane >> 4, c = lane & 15;
    const int ntile = wid >> 5;
    const int kstep = wid & 31;
    const int n = ntile * 16 + c;                   // 0..191
    const int m = n >> 6;
    const float* W = (m == 0) ? Wq : (m == 1) ? Wk : Wv;
    const int ncol = n & 63;
    const int k0 = kstep * 32 + q * 8;
    u16x8 pk;
#pragma unroll
    for (int j = 0; j < 8; j++) pk[j] = f32_to_bf16(W[(size_t)(k0 + j) * H_ + ncol]);
    *(u16x8*)(Wt + (size_t)wid * 512 + lane * 8) = pk;
}

// ---- Kernel 1: FUSED proj+attn (producer/consumer overlap) -----------------
// Round-21: proj (memory-service-bound, pipes idle, ~40us external floor) and
// attn (compute-bound, ~6MB traffic) ran sequentially. Fuse them:
//  - grid 1024x256, launch_bounds(256,4), LDS 36KB -> 4 blocks/CU -> the
//    ENTIRE grid is co-resident -> spin-waits cannot deadlock.
//  - producers (blocks 0..255): 4 proj panels each (measured-best proj code),
//    SELF-PACED per batch (batch b waits for batch b-1's flags) so batches
//    complete progressively (~11/22/33/41us) instead of all at ~40us.
//    Release: __syncthreads (drains all waves' stores to L2) -> __threadfence
//    (wbl2: flush to L3 = cross-XCD coherence point) -> atomicAdd(segcnt).
//  - consumers (all blocks; producers join after signaling): 2 passes over
//    units j=(b,ks,qt), batch-major ascending; spin on segcnt[b*8+ks] and
//    segcnt[b*8+g] (relaxed agent atomic loads + sched_barrier(0) ordering);
//    then the round-8 attn body unchanged. First-ever reads of Qf/Kf/Vf miss
//    local L2 and hit fresh L3 (launch-acquire killed pre-launch stale lines),
//    so no consumer-side invalidate is needed.
__global__ __launch_bounds__(256, 4) void fused_kernel(
    const float* __restrict__ x, const unsigned short* __restrict__ Wt,
    unsigned short* __restrict__ Qf, unsigned short* __restrict__ Kf,
    unsigned short* __restrict__ Vf, unsigned short* __restrict__ Opg,
    float* __restrict__ mlg, unsigned int* __restrict__ segcnt)
{
    __shared__ __align__(16) unsigned short xs[16][16][72];  // 36864 B
    const int bid  = blockIdx.x;
    const int t    = threadIdx.x;
    const int w    = t >> 6;
    const int lane = t & 63;
    const int quad = lane >> 4;
    const int c    = lane & 15;

    // ================= producer phase: proj, 4 panels per block =============
    if (bid < 256) {
        const int pb = bid >> 6;          // producer batch 0..3
        if (pb > 0) {
            // self-paced stagger: wait for previous batch fully projected
            for (;;) {
                unsigned int done = 0;
#pragma unroll
                for (int s = 0; s < 8; ++s)
                    done += __hip_atomic_load(&segcnt[(pb - 1) * 8 + s],
                                              __ATOMIC_RELAXED, __HIP_MEMORY_SCOPE_AGENT);
                if (done >= 64) break;
                __builtin_amdgcn_s_sleep(32);
            }
            __builtin_amdgcn_sched_barrier(0);
        }
        const int nh   = w * 48;          // wave's 48-col n-chunk
        const int row  = t >> 4;          // 16 rows, 16 threads/row
        const int koff = (t & 15) * 4;    // one f32x4 per thread per 64-col tile

        for (int pp = 0; pp < 4; ++pp) {
            const int r0 = (bid * 4 + pp) * 16;
            const float* xp = x + (size_t)(r0 + row) * C_ + koff;
            f32x4 xv[16];                 // static-indexed (full unroll) -> regs
#pragma unroll
            for (int p = 0; p < 16; p++) xv[p] = *(const f32x4*)(xp + 64 * p);
            if (pp) __syncthreads();      // previous panel's xs readers done
#pragma unroll
            for (int p = 0; p < 16; p++) {
                u16x4 pk;
#pragma unroll
                for (int i = 0; i < 4; i++) pk[i] = f32_to_bf16(xv[p][i]);
                *(u16x4*)&xs[p][row][koff] = pk;
            }
            __syncthreads();              // xs ready

            f32x4 acc[3];
#pragma unroll
            for (int j = 0; j < 3; j++) acc[j] = {0.f, 0.f, 0.f, 0.f};
#pragma unroll
            for (int p = 0; p < 16; p++) {
#pragma unroll
                for (int ks = 0; ks < 64; ks += 32) {
                    const bf16x8 a0 = *(const bf16x8*)&xs[p][c][ks + quad * 8];
                    const unsigned short* bp =
                        Wt + ((size_t)(nh >> 4) * 32 + ((p * 64 + ks) >> 5)) * 512 + lane * 8;
#pragma unroll
                    for (int j = 0; j < 3; j++) {
                        const bf16x8 bj = *(const bf16x8*)(bp + (size_t)j * 32 * 512);
                        acc[j] = __builtin_amdgcn_mfma_f32_16x16x32_bf16(a0, bj, acc[j], 0, 0, 0);
                    }
                }
            }
            // fused fragment-order epilogue (S = r0; 16-aligned)
            const int S   = r0;
            const int bS  = S >> 12;
            const int cc0 = quad * 4;
#pragma unroll
            for (int j = 0; j < 3; j++) {
                const int nt = nh + j * 16;
                if (nt < 128) {           // Q (nt<64) or K
                    const int d0 = (nt < 64) ? nt : nt - 64;
                    unsigned short* base = (nt < 64) ? Qf : Kf;
                    const int t16  = (S & 4095) >> 4;
                    const int half = d0 >> 5;
                    const int q8   = ((d0 >> 4) & 1) * 2 + (c >> 3);
                    const int j8   = c & 7;
                    unsigned short* pq = base + ((size_t)(bS * 256 + t16)) * 1024
                                       + half * 512 + q8 * 128 + j8;
#pragma unroll
                    for (int r = 0; r < 4; r++) pq[(cc0 + r) * 8] = f32_to_bf16(acc[j][r]);
                } else {                  // V
                    const int d0  = nt - 128;
                    const int k32 = (S & 4095) >> 5;
                    const int ht  = d0 >> 4;
                    const int sq  = (S & 31) >> 3;
                    unsigned short* pv = Vf + (((size_t)(bS * 128 + k32)) * 4 + ht) * 512 + c * 8;
#pragma unroll
                    for (int r = 0; r < 4; r++) {
                        const int cc = cc0 + r;
                        pv[(sq + (cc >> 3)) * 128 + (cc & 7)] = f32_to_bf16(acc[j][r]);
                    }
                }
            }
        }
        __syncthreads();                  // all waves' stores drained to L2
        if (t == 0) {
            __threadfence();              // flush dirty L2 -> L3 (coherence point)
            atomicAdd(&segcnt[bid >> 3], 1u);   // seg = rows 64*bid..+63 (one 512-seg)
        }
    }

    // ================= consumer phase: attn units ============================
    // slot in 0..4095; units j = slot + pass*4096 over (b,ks,qtc).
    const int slot = (bid >= 256) ? ((bid - 256) * 4 + w) : (3072 + bid * 4 + w);
    const float scale2 = 0.045084436f;    // (1/32)*log2(e)
    unsigned short* P = &xs[0][0][0] + w * 1152;   // per-wave 16x72 region
    const int prow = c * 72;

    for (int pass = 0; pass < 2; ++pass) {
        const int j  = slot + pass * 4096;
        const int b  = j >> 11;
        const int ks = (j >> 8) & 7;
        const int qt = 255 - (j & 255);
        const int g  = qt >> 5;
        if (ks > g) continue;

        // spin until K/V seg ks and Q seg g of batch b are projected
        const int f1 = b * 8 + ks, f2 = b * 8 + g;
        while (__hip_atomic_load(&segcnt[f1], __ATOMIC_RELAXED, __HIP_MEMORY_SCOPE_AGENT) < 8u ||
               __hip_atomic_load(&segcnt[f2], __ATOMIC_RELAXED, __HIP_MEMORY_SCOPE_AGENT) < 8u)
            __builtin_amdgcn_s_sleep(32);
        __builtin_amdgcn_sched_barrier(0);

        const int q0   = qt * 16;
        const int k0   = ks * 512;
        const int kend = (q0 + 15 < k0 + 511) ? q0 + 15 : k0 + 511;

        const unsigned short* qp = Qf + ((size_t)b * 256 + qt) * 1024 + lane * 8;
        const bf16x8 qB0 = *(const bf16x8*)qp;
        const bf16x8 qB1 = *(const bf16x8*)(qp + 512);

        f32x4 O[4];
#pragma unroll
        for (int tt = 0; tt < 4; tt++) O[tt] = {0.f, 0.f, 0.f, 0.f};
        float m = -1e30f, ls = 0.f;

        bf16x8 kC[8];
        {
            const unsigned short* kfb = Kf + ((size_t)b * 256 + (k0 >> 4)) * 1024 + lane * 8;
#pragma unroll
            for (int i = 0; i < 4; i++) {
                kC[2 * i]     = *(const bf16x8*)(kfb + i * 1024);
                kC[2 * i + 1] = *(const bf16x8*)(kfb + i * 1024 + 512);
            }
        }

        for (int kb = k0; kb <= kend; kb += 64) {
            f32x4 S[4];
            __builtin_amdgcn_s_setprio(1);
#pragma unroll
            for (int tt = 0; tt < 4; tt++) {
                f32x4 s = {0.f, 0.f, 0.f, 0.f};
                s = __builtin_amdgcn_mfma_f32_16x16x32_bf16(kC[2 * tt],     qB0, s, 0, 0, 0);
                s = __builtin_amdgcn_mfma_f32_16x16x32_bf16(kC[2 * tt + 1], qB1, s, 0, 0, 0);
                S[tt] = s;
            }
            __builtin_amdgcn_s_setprio(0);
            if (kb + 64 <= kend) {        // in-place K prefetch
                const unsigned short* kfb =
                    Kf + ((size_t)b * 256 + ((kb + 64) >> 4)) * 1024 + lane * 8;
#pragma unroll
                for (int i = 0; i < 4; i++) {
                    kC[2 * i]     = *(const bf16x8*)(kfb + i * 1024);
                    kC[2 * i + 1] = *(const bf16x8*)(kfb + i * 1024 + 512);
                }
            }
            // early V issue: latency hides under softmax
            const unsigned short* vfb = Vf + ((size_t)b * 128 + (kb >> 5)) * 2048 + lane * 8;
            const bf16x8 vC0 = *(const bf16x8*)(vfb + 0 * 512);
            const bf16x8 vC1 = *(const bf16x8*)(vfb + 1 * 512);
            const bf16x8 vC2 = *(const bf16x8*)(vfb + 2 * 512);
            const bf16x8 vC3 = *(const bf16x8*)(vfb + 3 * 512);
            const bf16x8 vC4 = *(const bf16x8*)(vfb + 2048 + 0 * 512);
            const bf16x8 vC5 = *(const bf16x8*)(vfb + 2048 + 1 * 512);
            const bf16x8 vC6 = *(const bf16x8*)(vfb + 2048 + 2 * 512);
            const bf16x8 vC7 = *(const bf16x8*)(vfb + 2048 + 3 * 512);

            if (kb + 63 > q0) {           // causal mask, raw domain
#pragma unroll
                for (int tt = 0; tt < 4; tt++)
#pragma unroll
                    for (int r = 0; r < 4; r++) {
                        const int key = kb + tt * 16 + quad * 4 + r;
                        if (key > q0 + c) S[tt][r] = -1e30f;
                    }
            }

            float t0 = fmaxf(fmaxf(S[0][0], S[0][1]), fmaxf(S[0][2], S[0][3]));
            float t1 = fmaxf(fmaxf(S[1][0], S[1][1]), fmaxf(S[1][2], S[1][3]));
            float t2 = fmaxf(fmaxf(S[2][0], S[2][1]), fmaxf(S[2][2], S[2][3]));
            float t3 = fmaxf(fmaxf(S[3][0], S[3][1]), fmaxf(S[3][2], S[3][3]));
            float mx = fmaxf(fmaxf(t0, t1), fmaxf(t2, t3));
            mx = fmaxf(mx, __shfl_xor(mx, 16));
            mx = fmaxf(mx, __shfl_xor(mx, 32));
            const float mxs = mx * scale2;

            if (__any(mxs > m)) {         // exact defer-rescale
                const float mn    = fmaxf(m, mxs);
                const float alpha = exp2_hw(m - mn);
                m = mn;
                ls *= alpha;
#pragma unroll
                for (int tt = 0; tt < 4; tt++)
#pragma unroll
                    for (int r = 0; r < 4; r++) O[tt][r] *= alpha;
            }

            float lp0 = 0.f, lp1 = 0.f, lp2 = 0.f, lp3 = 0.f;
#pragma unroll
            for (int tt = 0; tt < 4; tt++) {
                const float e0 = exp2_hw(fmaf(S[tt][0], scale2, -m));
                const float e1 = exp2_hw(fmaf(S[tt][1], scale2, -m));
                const float e2 = exp2_hw(fmaf(S[tt][2], scale2, -m));
                const float e3 = exp2_hw(fmaf(S[tt][3], scale2, -m));
                const float l  = (e0 + e1) + (e2 + e3);
                if (tt == 0) lp0 = l; else if (tt == 1) lp1 = l;
                else if (tt == 2) lp2 = l; else lp3 = l;
                u32x2 pw;
                pw[0] = cvt_pk_bf16(e0, e1);
                pw[1] = cvt_pk_bf16(e2, e3);
                *(u32x2*)(P + prow + tt * 16 + quad * 4) = pw;
            }
            ls += (lp0 + lp1) + (lp2 + lp3);

            const bf16x8 pB0 = *(const bf16x8*)(P + prow + quad * 8);
            const bf16x8 pB1 = *(const bf16x8*)(P + prow + 32 + quad * 8);

            __builtin_amdgcn_s_setprio(1);
            O[0] = __builtin_amdgcn_mfma_f32_16x16x32_bf16(vC0, pB0, O[0], 0, 0, 0);
            O[0] = __builtin_amdgcn_mfma_f32_16x16x32_bf16(vC4, pB1, O[0], 0, 0, 0);
            O[1] = __builtin_amdgcn_mfma_f32_16x16x32_bf16(vC1, pB0, O[1], 0, 0, 0);
            O[1] = __builtin_amdgcn_mfma_f32_16x16x32_bf16(vC5, pB1, O[1], 0, 0, 0);
            O[2] = __builtin_amdgcn_mfma_f32_16x16x32_bf16(vC2, pB0, O[2], 0, 0, 0);
            O[2] = __builtin_amdgcn_mfma_f32_16x16x32_bf16(vC6, pB1, O[2], 0, 0, 0);
            O[3] = __builtin_amdgcn_mfma_f32_16x16x32_bf16(vC3, pB0, O[3], 0, 0, 0);
            O[3] = __builtin_amdgcn_mfma_f32_16x16x32_bf16(vC7, pB1, O[3], 0, 0, 0);
            __builtin_amdgcn_s_setprio(0);
        }

        ls += __shfl_xor(ls, 16);
        ls += __shfl_xor(ls, 32);

        const size_t ustore = (size_t)b * NUNIT_ + qt + 16 * g * (g - 1) + g * (qt & 31) + ks;
#pragma unroll
        for (int tt = 0; tt < 4; tt++) {
            u32x2 pw;
            pw[0] = cvt_pk_bf16(O[tt][0], O[tt][1]);
            pw[1] = cvt_pk_bf16(O[tt][2], O[tt][3]);
            *(u32x2*)(Opg + ustore * 1024 + c * 64 + tt * 16 + quad * 4) = pw;
        }
        if (lane < 16) {
            mlg[ustore * 32 + c]      = m;
            mlg[ustore * 32 + 16 + c] = ls;
        }
    }
}

// ---- Kernel 3: merge segments + normalize (unchanged) ----------------------
__global__ __launch_bounds__(256) void merge_kernel(
    const unsigned short* __restrict__ Opg, const float* __restrict__ mlg,
    float* __restrict__ out)
{
    const int idx = blockIdx.x;               // b*256 + qt
    const int b   = idx >> 8;
    const int qt  = idx & 255;
    const int g   = qt >> 5;
    const int nseg = g + 1;
    const size_t base = (size_t)b * NUNIT_ + qt + 16 * g * (g - 1) + g * (qt & 31);
    const int t  = threadIdx.x;
    const int h  = t & 63;
    const int rg = t >> 6;
#pragma unroll
    for (int i = 0; i < 4; i++) {
        const int row = rg * 4 + i;
        float M = -1e30f;
        for (int s = 0; s < nseg; s++) M = fmaxf(M, mlg[(base + s) * 32 + row]);
        float L = 0.f, val = 0.f;
        for (int s = 0; s < nseg; s++) {
            const float e = exp2_hw(mlg[(base + s) * 32 + row] - M);
            L   = fmaf(mlg[(base + s) * 32 + 16 + row], e, L);
            val = fmaf(bf16_to_f32(Opg[(base + s) * 1024 + row * 64 + h]), e, val);
        }
        out[((size_t)b * T_ + qt * 16 + row) * H_ + h] = val / L;
    }
}

extern "C" void kernel_launch(void* const* d_in, const int* in_sizes, int n_in,
                              void* d_out, int out_size, void* d_ws, size_t ws_size,
                              hipStream_t stream) {
    const float* x  = (const float*)d_in[0];
    const float* Wq = (const float*)d_in[1];
    const float* Wk = (const float*)d_in[2];
    const float* Wv = (const float*)d_in[3];
    float* out = (float*)d_out;

    // ws: Qf|Kf|Vf (2 MiB each) | Wt 384K | Opg 9.2 MiB | mlg 576K | segcnt 128B
    unsigned short* Qf = (unsigned short*)d_ws;
    unsigned short* Kf = Qf + (size_t)BT_ * H_;
    unsigned short* Vf = Kf + (size_t)BT_ * H_;
    unsigned short* Wt = Vf + (size_t)BT_ * H_;
    unsigned short* Opg = Wt + (size_t)192 * C_;
    float*          mlg = (float*)(Opg + (size_t)B_ * NUNIT_ * 1024);
    unsigned int*   segcnt = (unsigned int*)(mlg + (size_t)B_ * NUNIT_ * 32);

    wconv_kernel<<<96, 256, 0, stream>>>(Wq, Wk, Wv, Wt, segcnt);
    fused_kernel<<<1024, 256, 0, stream>>>(x, Wt, Qf, Kf, Vf, Opg, mlg, segcnt);
    merge_kernel<<<1024, 256, 0, stream>>>(Opg, mlg, out);
}

// Round 10
// 157.015 us; speedup vs baseline: 3.8320x; 3.8320x over previous
//
#include <hip/hip_runtime.h>

constexpr int B_  = 4;
constexpr int T_  = 4096;
constexpr int C_  = 1024;
constexpr int H_  = 64;
constexpr int BT_ = B_ * T_;
constexpr int NUNIT_ = 1152;   // 512-key work units per batch: sum_qt (qt/32+1)

typedef __attribute__((ext_vector_type(4))) float f32x4;
typedef __attribute__((ext_vector_type(8))) short bf16x8;
typedef __attribute__((ext_vector_type(8))) unsigned short u16x8;
typedef __attribute__((ext_vector_type(4))) unsigned short u16x4;
typedef __attribute__((ext_vector_type(2))) unsigned int u32x2;

__device__ __forceinline__ unsigned short f32_to_bf16(float f) {
    union { float f; unsigned int u; } v;
    v.f = f;
    unsigned int r = v.u + 0x7FFFu + ((v.u >> 16) & 1u);  // RNE
    return (unsigned short)(r >> 16);
}
__device__ __forceinline__ float bf16_to_f32(unsigned short us) {
    union { unsigned int u; float f; } v;
    v.u = (unsigned int)us << 16;
    return v.f;
}
// 2^x via v_exp_f32 (hardware transcendental); __exp2f does not exist in HIP.
__device__ __forceinline__ float exp2_hw(float x) {
    return __builtin_amdgcn_exp2f(x);
}
// HW packed f32->bf16 (RNE, same rounding as f32_to_bf16): 1 instr for 2 vals.
__device__ __forceinline__ unsigned int cvt_pk_bf16(float lo, float hi) {
    unsigned int r;
    asm("v_cvt_pk_bf16_f32 %0, %1, %2" : "=v"(r) : "v"(lo), "v"(hi));
    return r;
}

// ---- Kernel 0: W -> fragment-order Wt ------------------------------------
__global__ __launch_bounds__(256) void wconv_kernel(
    const float* __restrict__ Wq, const float* __restrict__ Wk,
    const float* __restrict__ Wv, unsigned short* __restrict__ Wt)
{
    const int tid  = threadIdx.x;
    const int wid  = blockIdx.x * 4 + (tid >> 6);   // 0..383 = 12 ntiles x 32 ksteps
    const int lane = tid & 63;
    const int q    = lane >> 4, c = lane & 15;
    const int ntile = wid >> 5;
    const int kstep = wid & 31;
    const int n = ntile * 16 + c;                   // 0..191
    const int m = n >> 6;
    const float* W = (m == 0) ? Wq : (m == 1) ? Wk : Wv;
    const int ncol = n & 63;
    const int k0 = kstep * 32 + q * 8;
    u16x8 pk;
#pragma unroll
    for (int j = 0; j < 8; j++) pk[j] = f32_to_bf16(W[(size_t)(k0 + j) * H_ + ncol]);
    *(u16x8*)(Wt + (size_t)wid * 512 + lane * 8) = pk;
}

// ---- Kernel 1: QKV projection (round-16/round-4 measured-best form) --------
// Whole-panel single-stage: 16 plain 16B loads in flight per thread (full
// 4KB sequential sweep per row), convert as they arrive into 36KB LDS, ONE
// __syncthreads, then 16 pure LDS+MFMA phases. proj is pinned at ~40us by
// the memory-system service rate for our cold reads (6 structures invariant;
// fills hit 6.5TB/s on the write path) - environmental floor.
__global__ __launch_bounds__(256, 4) void proj_kernel(
    const float* __restrict__ x, const unsigned short* __restrict__ Wt,
    unsigned short* __restrict__ Qf, unsigned short* __restrict__ Kf,
    unsigned short* __restrict__ Vf)
{
    __shared__ __align__(16) unsigned short xs[16][16][72];  // [phase][row][col+pad]
    const int t    = threadIdx.x;
    const int r0   = blockIdx.x * 16;
    const int w    = t >> 6;             // 0..3
    const int lane = t & 63;
    const int quad = lane >> 4;
    const int c    = lane & 15;
    const int nh   = w * 48;             // wave's 48-col n-chunk
    const int row  = t >> 4;             // 16 rows, 16 threads/row
    const int koff = (t & 15) * 4;       // one f32x4 per thread per 64-col tile

    // ---- stage: 16 loads in flight, convert as they arrive, one barrier ----
    const float* xp = x + (size_t)(r0 + row) * C_ + koff;
    f32x4 xv[16];                        // static-indexed (full unroll) -> regs
#pragma unroll
    for (int p = 0; p < 16; p++) xv[p] = *(const f32x4*)(xp + 64 * p);
#pragma unroll
    for (int p = 0; p < 16; p++) {
        u16x4 pk;
#pragma unroll
        for (int i = 0; i < 4; i++) pk[i] = f32_to_bf16(xv[p][i]);
        *(u16x4*)&xs[p][row][koff] = pk;
    }
    __syncthreads();                     // the only barrier in the kernel

    // ---- compute: 16 phases, pure LDS + MFMA, no barriers ----
    f32x4 acc[3];
#pragma unroll
    for (int j = 0; j < 3; j++) acc[j] = {0.f, 0.f, 0.f, 0.f};

#pragma unroll
    for (int p = 0; p < 16; p++) {
#pragma unroll
        for (int ks = 0; ks < 64; ks += 32) {
            const bf16x8 a0 = *(const bf16x8*)&xs[p][c][ks + quad * 8];
            const unsigned short* bp =
                Wt + ((size_t)(nh >> 4) * 32 + ((p * 64 + ks) >> 5)) * 512 + lane * 8;
#pragma unroll
            for (int j = 0; j < 3; j++) {
                const bf16x8 bj = *(const bf16x8*)(bp + (size_t)j * 32 * 512);
                acc[j] = __builtin_amdgcn_mfma_f32_16x16x32_bf16(a0, bj, acc[j], 0, 0, 0);
            }
        }
    }

    // fused fragment-order epilogue (S = r0; 16-aligned)
    const int S   = r0;
    const int bS  = S >> 12;
    const int cc0 = quad * 4;
#pragma unroll
    for (int j = 0; j < 3; j++) {
        const int nt = nh + j * 16;   // wave-uniform matrix select
        if (nt < 128) {               // Q (nt<64) or K
            const int d0 = (nt < 64) ? nt : nt - 64;
            unsigned short* base = (nt < 64) ? Qf : Kf;
            const int t16  = (S & 4095) >> 4;
            const int half = d0 >> 5;
            const int q8   = ((d0 >> 4) & 1) * 2 + (c >> 3);
            const int j8   = c & 7;
            unsigned short* pq = base + ((size_t)(bS * 256 + t16)) * 1024
                               + half * 512 + q8 * 128 + j8;
#pragma unroll
            for (int r = 0; r < 4; r++) pq[(cc0 + r) * 8] = f32_to_bf16(acc[j][r]);
        } else {                      // V
            const int d0  = nt - 128;
            const int k32 = (S & 4095) >> 5;
            const int ht  = d0 >> 4;
            const int sq  = (S & 31) >> 3;   // 0 or 2
            unsigned short* pv = Vf + (((size_t)(bS * 128 + k32)) * 4 + ht) * 512 + c * 8;
#pragma unroll
            for (int r = 0; r < 4; r++) {
                const int cc = cc0 + r;
                pv[(sq + (cc >> 3)) * 128 + (cc & 7)] = f32_to_bf16(acc[j][r]);
            }
        }
    }
}

// ---- Kernel 2: causal flash attention (round-8/round-20 measured best) -----
// Early-V issue + in-place K prefetch + s_setprio around MFMA clusters +
// raw-domain softmax (cndmask mask, one scale mul, fma-folded exp arg) +
// v_cvt_pk_bf16_f32 packing + exact defer-rescale.
// Unit = wave = (b, qt, ks): queries qt*16..+15, keys [ks*512, ks*512+512).
__global__ __launch_bounds__(256) void attn_kernel(
    const unsigned short* __restrict__ Qf, const unsigned short* __restrict__ Kf,
    const unsigned short* __restrict__ Vf, unsigned short* __restrict__ Opg,
    float* __restrict__ mlg)
{
    __shared__ __align__(16) unsigned short Pb[4][16][72];
    const int tid  = threadIdx.x;
    const int w    = tid >> 6;
    const int lane = tid & 63;
    const int quad = lane >> 4;
    const int c    = lane & 15;
    const int bid  = blockIdx.x;
    const int qt   = 255 - (bid & 255);       // qt descending within ks-group
    const int ks   = bid >> 8;
    const int g    = qt >> 5;                 // nseg-1
    if (ks > g) return;
    const int b    = w;                       // wave = batch (equal work lengths)
    const int q0   = qt * 16;
    const int k0   = ks * 512;
    const int kend = (q0 + 15 < k0 + 511) ? q0 + 15 : k0 + 511;

    // Q B-frags: coalesced 1KB wave loads from fragment-order Qf
    const unsigned short* qp = Qf + ((size_t)b * 256 + qt) * 1024 + lane * 8;
    const bf16x8 qB0 = *(const bf16x8*)qp;
    const bf16x8 qB1 = *(const bf16x8*)(qp + 512);

    f32x4 O[4];
#pragma unroll
    for (int tt = 0; tt < 4; tt++) O[tt] = {0.f, 0.f, 0.f, 0.f};
    float m = -1e30f, ls = 0.f;
    const float scale2 = 0.045084436f;        // (1/32)*log2(e): exp -> exp2

    unsigned short* P = &Pb[w][0][0];
    const int prow = c * 72;

    // preload first K chunk
    bf16x8 kC[8];
    {
        const unsigned short* kfb = Kf + ((size_t)b * 256 + (k0 >> 4)) * 1024 + lane * 8;
#pragma unroll
        for (int i = 0; i < 4; i++) {
            kC[2 * i]     = *(const bf16x8*)(kfb + i * 1024);
            kC[2 * i + 1] = *(const bf16x8*)(kfb + i * 1024 + 512);
        }
    }

    for (int kb = k0; kb <= kend; kb += 64) {
        f32x4 S[4];
        __builtin_amdgcn_s_setprio(1);
#pragma unroll
        for (int tt = 0; tt < 4; tt++) {
            f32x4 s = {0.f, 0.f, 0.f, 0.f};
            s = __builtin_amdgcn_mfma_f32_16x16x32_bf16(kC[2 * tt],     qB0, s, 0, 0, 0);
            s = __builtin_amdgcn_mfma_f32_16x16x32_bf16(kC[2 * tt + 1], qB1, s, 0, 0, 0);
            S[tt] = s;
        }
        __builtin_amdgcn_s_setprio(0);
        // in-place prefetch of next chunk's K (kC already consumed above);
        // latency hides under softmax + PV below.
        if (kb + 64 <= kend) {
            const unsigned short* kfb =
                Kf + ((size_t)b * 256 + ((kb + 64) >> 4)) * 1024 + lane * 8;
#pragma unroll
            for (int i = 0; i < 4; i++) {
                kC[2 * i]     = *(const bf16x8*)(kfb + i * 1024);
                kC[2 * i + 1] = *(const bf16x8*)(kfb + i * 1024 + 512);
            }
        }
        // EARLY V issue for the current chunk: latency hides under softmax.
        const unsigned short* vfb = Vf + ((size_t)b * 128 + (kb >> 5)) * 2048 + lane * 8;
        const bf16x8 vC0 = *(const bf16x8*)(vfb + 0 * 512);
        const bf16x8 vC1 = *(const bf16x8*)(vfb + 1 * 512);
        const bf16x8 vC2 = *(const bf16x8*)(vfb + 2 * 512);
        const bf16x8 vC3 = *(const bf16x8*)(vfb + 3 * 512);
        const bf16x8 vC4 = *(const bf16x8*)(vfb + 2048 + 0 * 512);
        const bf16x8 vC5 = *(const bf16x8*)(vfb + 2048 + 1 * 512);
        const bf16x8 vC6 = *(const bf16x8*)(vfb + 2048 + 2 * 512);
        const bf16x8 vC7 = *(const bf16x8*)(vfb + 2048 + 3 * 512);

        // causal mask in RAW domain: pure cndmask, no multiplies
        if (kb + 63 > q0) {                   // diagonal chunk
#pragma unroll
            for (int tt = 0; tt < 4; tt++)
#pragma unroll
                for (int r = 0; r < 4; r++) {
                    const int key = kb + tt * 16 + quad * 4 + r;
                    if (key > q0 + c) S[tt][r] = -1e30f;
                }
        }

        // tree max on raw S (clang fuses nested fmaxf to v_max3)
        float t0 = fmaxf(fmaxf(S[0][0], S[0][1]), fmaxf(S[0][2], S[0][3]));
        float t1 = fmaxf(fmaxf(S[1][0], S[1][1]), fmaxf(S[1][2], S[1][3]));
        float t2 = fmaxf(fmaxf(S[2][0], S[2][1]), fmaxf(S[2][2], S[2][3]));
        float t3 = fmaxf(fmaxf(S[3][0], S[3][1]), fmaxf(S[3][2], S[3][3]));
        float mx = fmaxf(fmaxf(t0, t1), fmaxf(t2, t3));
        mx = fmaxf(mx, __shfl_xor(mx, 16));
        mx = fmaxf(mx, __shfl_xor(mx, 32));
        const float mxs = mx * scale2;        // ONE scale mul per chunk

        // exact defer-rescale: alpha==1 when mxs<=m for all lanes
        if (__any(mxs > m)) {
            const float mn    = fmaxf(m, mxs);
            const float alpha = exp2_hw(m - mn);
            m = mn;
            ls *= alpha;
#pragma unroll
            for (int tt = 0; tt < 4; tt++)
#pragma unroll
                for (int r = 0; r < 4; r++) O[tt][r] *= alpha;
        }

        // exp (scale folded into fma) + HW packed bf16 convert + P write
        float lp0 = 0.f, lp1 = 0.f, lp2 = 0.f, lp3 = 0.f;
#pragma unroll
        for (int tt = 0; tt < 4; tt++) {
            const float e0 = exp2_hw(fmaf(S[tt][0], scale2, -m));
            const float e1 = exp2_hw(fmaf(S[tt][1], scale2, -m));
            const float e2 = exp2_hw(fmaf(S[tt][2], scale2, -m));
            const float e3 = exp2_hw(fmaf(S[tt][3], scale2, -m));
            const float l  = (e0 + e1) + (e2 + e3);
            if (tt == 0) lp0 = l; else if (tt == 1) lp1 = l;
            else if (tt == 2) lp2 = l; else lp3 = l;
            u32x2 pw;
            pw[0] = cvt_pk_bf16(e0, e1);
            pw[1] = cvt_pk_bf16(e2, e3);
            *(u32x2*)(P + prow + tt * 16 + quad * 4) = pw;   // P[query][key]
        }
        ls += (lp0 + lp1) + (lp2 + lp3);

        const bf16x8 pB0 = *(const bf16x8*)(P + prow + quad * 8);
        const bf16x8 pB1 = *(const bf16x8*)(P + prow + 32 + quad * 8);

        __builtin_amdgcn_s_setprio(1);
        O[0] = __builtin_amdgcn_mfma_f32_16x16x32_bf16(vC0, pB0, O[0], 0, 0, 0);
        O[0] = __builtin_amdgcn_mfma_f32_16x16x32_bf16(vC4, pB1, O[0], 0, 0, 0);
        O[1] = __builtin_amdgcn_mfma_f32_16x16x32_bf16(vC1, pB0, O[1], 0, 0, 0);
        O[1] = __builtin_amdgcn_mfma_f32_16x16x32_bf16(vC5, pB1, O[1], 0, 0, 0);
        O[2] = __builtin_amdgcn_mfma_f32_16x16x32_bf16(vC2, pB0, O[2], 0, 0, 0);
        O[2] = __builtin_amdgcn_mfma_f32_16x16x32_bf16(vC6, pB1, O[2], 0, 0, 0);
        O[3] = __builtin_amdgcn_mfma_f32_16x16x32_bf16(vC3, pB0, O[3], 0, 0, 0);
        O[3] = __builtin_amdgcn_mfma_f32_16x16x32_bf16(vC7, pB1, O[3], 0, 0, 0);
        __builtin_amdgcn_s_setprio(0);
    }

    ls += __shfl_xor(ls, 16);                 // total l for query c
    ls += __shfl_xor(ls, 32);

    const size_t ustore = (size_t)b * NUNIT_ + qt + 16 * g * (g - 1) + g * (qt & 31) + ks;
#pragma unroll
    for (int tt = 0; tt < 4; tt++) {
        u32x2 pw;
        pw[0] = cvt_pk_bf16(O[tt][0], O[tt][1]);
        pw[1] = cvt_pk_bf16(O[tt][2], O[tt][3]);
        *(u32x2*)(Opg + ustore * 1024 + c * 64 + tt * 16 + quad * 4) = pw;
    }
    if (lane < 16) {
        mlg[ustore * 32 + c]      = m;        // log2-domain max
        mlg[ustore * 32 + 16 + c] = ls;
    }
}

// ---- Kernel 3: merge segments + normalize --------------------------------
__global__ __launch_bounds__(256) void merge_kernel(
    const unsigned short* __restrict__ Opg, const float* __restrict__ mlg,
    float* __restrict__ out)
{
    const int idx = blockIdx.x;               // b*256 + qt
    const int b   = idx >> 8;
    const int qt  = idx & 255;
    const int g   = qt >> 5;
    const int nseg = g + 1;
    const size_t base = (size_t)b * NUNIT_ + qt + 16 * g * (g - 1) + g * (qt & 31);
    const int t  = threadIdx.x;
    const int h  = t & 63;
    const int rg = t >> 6;
#pragma unroll
    for (int i = 0; i < 4; i++) {
        const int row = rg * 4 + i;
        float M = -1e30f;
        for (int s = 0; s < nseg; s++) M = fmaxf(M, mlg[(base + s) * 32 + row]);
        float L = 0.f, val = 0.f;
        for (int s = 0; s < nseg; s++) {
            const float e = exp2_hw(mlg[(base + s) * 32 + row] - M);
            L   = fmaf(mlg[(base + s) * 32 + 16 + row], e, L);
            val = fmaf(bf16_to_f32(Opg[(base + s) * 1024 + row * 64 + h]), e, val);
        }
        out[((size_t)b * T_ + qt * 16 + row) * H_ + h] = val / L;
    }
}

extern "C" void kernel_launch(void* const* d_in, const int* in_sizes, int n_in,
                              void* d_out, int out_size, void* d_ws, size_t ws_size,
                              hipStream_t stream) {
    const float* x  = (const float*)d_in[0];
    const float* Wq = (const float*)d_in[1];
    const float* Wk = (const float*)d_in[2];
    const float* Wv = (const float*)d_in[3];
    float* out = (float*)d_out;

    // ws: Qf|Kf|Vf (2 MiB each) | Wt 384K | Opg 9.2 MiB | mlg 576K
    unsigned short* Qf = (unsigned short*)d_ws;
    unsigned short* Kf = Qf + (size_t)BT_ * H_;
    unsigned short* Vf = Kf + (size_t)BT_ * H_;
    unsigned short* Wt = Vf + (size_t)BT_ * H_;
    unsigned short* Opg = Wt + (size_t)192 * C_;
    float*          mlg = (float*)(Opg + (size_t)B_ * NUNIT_ * 1024);

    wconv_kernel<<<96, 256, 0, stream>>>(Wq, Wk, Wv, Wt);
    proj_kernel<<<1024, 256, 0, stream>>>(x, Wt, Qf, Kf, Vf);
    attn_kernel<<<2048, 256, 0, stream>>>(Qf, Kf, Vf, Opg, mlg);
    merge_kernel<<<1024, 256, 0, stream>>>(Opg, mlg, out);
}